// Round 5
// baseline (242.526 us; speedup 1.0000x reference)
//
#include <hip/hip_runtime.h>

#define CH    288
#define CPG   9
#define IMH   64
#define IMW   64
#define HW    4096
#define NB    8
#define NTILE 128            // 32-px tiles per image
#define TILEB 18432u         // bytes per x_p tile (9 slabs x 2048 B)
#define BN_EPS 1e-5f

typedef short bf16x8 __attribute__((ext_vector_type(8)));
typedef float f32x4  __attribute__((ext_vector_type(4)));

// ws layout (bytes)
#define XP_OFF   0u            // x_p / tmp_p bf16, k-chunk-major swizzled (18,874,368)
#define WIP_OFF  18874368u     // Wi_p  [9][288][64B] swizzled (165,888)
#define WOP_OFF  19040256u     // Wo_p  [9][288][64B] swizzled, scale-folded (165,888)
#define PART_OFF 19206144u     // per-block stats partials [1024][576] f32 (2,359,296)
#define SC_OFF   21565440u     // scale f32 [288]
#define SH_OFF   21566592u     // shift f32 [288]
#define BO2_OFF  21567744u     // folded bias f32 [288]

__device__ __forceinline__ unsigned short f2b(float f) {
    unsigned int u = __float_as_uint(f);
    return (unsigned short)((u + 0x7fffu + ((u >> 16) & 1u)) >> 16);
}
__device__ __forceinline__ float b2f(unsigned short h) {
    return __uint_as_float(((unsigned int)h) << 16);
}

// async global->LDS: 16B/lane, dst = wave-uniform base + lane*16.
// All call sites use CONTIGUOUS 1KB global segments (g = seg_base + lane*16).
#define GLDS(g, l) __builtin_amdgcn_global_load_lds( \
    (const __attribute__((address_space(1))) void*)(g), \
    (__attribute__((address_space(3))) void*)(l), 16, 0, 0)

__device__ __forceinline__ f32x4 mfma16(bf16x8 a, bf16x8 b, f32x4 c) {
    return __builtin_amdgcn_mfma_f32_16x16x32_bf16(a, b, c, 0, 0, 0);
}

// ---------------------------------------------------------------------------
// K0: x f32 [b][c][p] -> x_p bf16 [b*128+tile][k0][px 32][64B], chunk slot qq
// of row px holds source channels k0*32 + (qq^((px>>1)&3))*8 .. +8.
// ---------------------------------------------------------------------------
__global__ __launch_bounds__(256) void k_transpose(const float* __restrict__ x,
                                                   char* __restrict__ xp) {
    __shared__ unsigned short T[32 * 296];   // [px][c], 592 B rows
    const int tid = threadIdx.x;
    const int p0  = blockIdx.x * 32;
    const int b   = blockIdx.y;
    #pragma unroll 1
    for (int it = 0; it < 9; ++it) {
        const int c   = it * 32 + (tid >> 3);
        const int px4 = (tid & 7) * 4;
        const float4 v = *(const float4*)(x + (size_t)(b * CH + c) * HW + p0 + px4);
        T[(px4 + 0) * 296 + c] = f2b(v.x);
        T[(px4 + 1) * 296 + c] = f2b(v.y);
        T[(px4 + 2) * 296 + c] = f2b(v.z);
        T[(px4 + 3) * 296 + c] = f2b(v.w);
    }
    __syncthreads();
    char* tile = xp + (size_t)(b * NTILE + blockIdx.x) * TILEB;
    for (int idx = tid; idx < 1152; idx += 256) {
        const int k0 = idx >> 7;
        const int px = (idx >> 2) & 31;
        const int qq = idx & 3;
        *(uint4*)(tile + idx * 16) =
            *(const uint4*)((const char*)T + px * 592 + k0 * 64 +
                            ((qq ^ ((px >> 1) & 3)) * 16));
    }
}

// ---------------------------------------------------------------------------
// K0b: Wi f32 -> Wi_p bf16 [k0][c][64B] with chunk swizzle q^((c>>1)&3)
// ---------------------------------------------------------------------------
__global__ __launch_bounds__(256) void k_wi_pack(const float* __restrict__ Wi,
                                                 char* __restrict__ Wip) {
    const int idx = blockIdx.x * 256 + threadIdx.x;
    if (idx >= 10368) return;                  // 9*288*4 chunks
    const int k0  = idx / 1152;
    const int rem = idx - k0 * 1152;
    const int c   = rem >> 2;
    const int q   = rem & 3;
    const int sq  = q ^ ((c >> 1) & 3);
    const float* src = Wi + (size_t)c * CH + k0 * 32 + sq * 8;
    const float4 a = *(const float4*)src;
    const float4 d = *(const float4*)(src + 4);
    unsigned short h[8] = {f2b(a.x), f2b(a.y), f2b(a.z), f2b(a.w),
                           f2b(d.x), f2b(d.y), f2b(d.z), f2b(d.w)};
    *(uint4*)(Wip + (size_t)idx * 16) = *(const uint4*)h;
}

// ---------------------------------------------------------------------------
// K1: MFMA GEMM1, contiguous-GLDS staging, atomic-free fused BN stats.
// Block = 32 px x 288 ch, 4 waves; wave = 16 px x 144 ch (9 tiles).
// LDS: [0,18432) Wi slab / T2-alias; [18432,20480) x slab; [20480,22784) stats.
// ---------------------------------------------------------------------------
__global__ __launch_bounds__(256) void k_gemm1(const char* __restrict__ Wip,
                                               const float* __restrict__ bi,
                                               char* __restrict__ xp,
                                               float* __restrict__ part) {
    __shared__ short smem[11392];              // 22784 B
    char* smc = (char*)smem;
    float* sstat = (float*)(smc + 20480);

    const int tid  = threadIdx.x;
    const int wave = tid >> 6;
    const int lane = tid & 63;
    const int q    = lane >> 4;
    const int r    = lane & 15;
    const int pxh  = wave & 1;
    const int chh  = wave >> 1;
    char* tile = xp + (size_t)(blockIdx.y * NTILE + blockIdx.x) * TILEB;

    for (int c2 = tid; c2 < 576; c2 += 256) sstat[c2] = 0.0f;

    f32x4 acc[9];
    #pragma unroll
    for (int j = 0; j < 9; ++j) acc[j] = (f32x4)0.0f;

    const int pxl = pxh * 16 + r;
    for (int k0 = 0; k0 < 9; ++k0) {
        for (int s = wave; s < 20; s += 4) {
            const char* g = (s < 18)
                ? Wip  + (size_t)k0 * TILEB + s * 1024 + lane * 16
                : tile + (size_t)k0 * 2048 + (s - 18) * 1024 + lane * 16;
            GLDS(g, smc + s * 1024);
        }
        __syncthreads();
        const bf16x8 xf = *(const bf16x8*)(smc + 18432 + pxl * 64 +
                                           ((q ^ ((pxl >> 1) & 3)) * 16));
        #pragma unroll
        for (int j = 0; j < 9; ++j) {
            const int row = chh * 144 + j * 16 + r;
            const bf16x8 wf = *(const bf16x8*)(smc + row * 64 +
                                               ((q ^ ((row >> 1) & 3)) * 16));
            acc[j] = mfma16(wf, xf, acc[j]);
        }
        __syncthreads();
    }

    // epilogue: bias+relu -> T2 staging [px 32][c 288] (592 B rows) + stats
    #pragma unroll 1
    for (int j = 0; j < 9; ++j) {
        const int cb = chh * 144 + j * 16 + q * 4;
        const float4 b4 = *(const float4*)(bi + cb);
        float v0 = fmaxf(acc[j][0] + b4.x, 0.0f);
        float v1 = fmaxf(acc[j][1] + b4.y, 0.0f);
        float v2 = fmaxf(acc[j][2] + b4.z, 0.0f);
        float v3 = fmaxf(acc[j][3] + b4.w, 0.0f);
        unsigned short h[4] = {f2b(v0), f2b(v1), f2b(v2), f2b(v3)};
        *(uint2*)(smc + pxl * 592 + cb * 2) = *(const uint2*)h;
        float a1[4] = {v0, v1, v2, v3};
        float a2[4] = {v0 * v0, v1 * v1, v2 * v2, v3 * v3};
        #pragma unroll
        for (int m = 1; m < 16; m <<= 1) {
            #pragma unroll
            for (int i = 0; i < 4; ++i) {
                a1[i] += __shfl_xor(a1[i], m, 64);
                a2[i] += __shfl_xor(a2[i], m, 64);
            }
        }
        if (r == 0) {
            #pragma unroll
            for (int i = 0; i < 4; ++i) {
                atomicAdd(&sstat[cb + i], a1[i]);
                atomicAdd(&sstat[288 + cb + i], a2[i]);
            }
        }
    }
    __syncthreads();

    // coalesced swizzled store of tmp tile (in-place over x_p tile)
    for (int idx = tid; idx < 1152; idx += 256) {
        const int k0 = idx >> 7;
        const int px = (idx >> 2) & 31;
        const int qq = idx & 3;
        *(uint4*)(tile + idx * 16) =
            *(const uint4*)(smc + px * 592 + k0 * 64 +
                            ((qq ^ ((px >> 1) & 3)) * 16));
    }
    // per-block stats partials (no global atomics)
    const int blkid = blockIdx.y * NTILE + blockIdx.x;
    for (int c2 = tid; c2 < 576; c2 += 256)
        part[(size_t)blkid * 576 + c2] = sstat[c2];
}

// ---------------------------------------------------------------------------
// K2a: reduce partials -> BN scale/shift
// ---------------------------------------------------------------------------
__global__ __launch_bounds__(576) void k_scale(const float* __restrict__ part,
                                               const float* __restrict__ gamma,
                                               const float* __restrict__ beta,
                                               float* __restrict__ scale,
                                               float* __restrict__ shift) {
    __shared__ float red[576];
    const int t = threadIdx.x;
    float s = 0.0f;
    for (int bk = 0; bk < NB * NTILE; ++bk) s += part[(size_t)bk * 576 + t];
    red[t] = s;
    __syncthreads();
    if (t < CH) {
        const float inv  = 1.0f / (float)(NB * HW);
        const float mean = red[t] * inv;
        const float var  = red[288 + t] * inv - mean * mean;
        const float rs   = rsqrtf(var + BN_EPS);
        const float sc   = gamma[t] * rs;
        scale[t] = sc;
        shift[t] = beta[t] - mean * sc;
    }
}

// ---------------------------------------------------------------------------
// K2b: Wo_p[k0][m][64B] = bf16(Wo[m][k]*scale[k]) swizzled; bo2 = bo + Wo@shift
// ---------------------------------------------------------------------------
__global__ __launch_bounds__(64) void k_fold(const float* __restrict__ Wo,
                                             const float* __restrict__ bo,
                                             const float* __restrict__ scale,
                                             const float* __restrict__ shift,
                                             char* __restrict__ Wop,
                                             float* __restrict__ bo2) {
    const int m = blockIdx.x;
    const int t = threadIdx.x;
    float s = 0.0f;
    for (int k = t; k < CH; k += 64) s += Wo[(size_t)m * CH + k] * shift[k];
    #pragma unroll
    for (int off = 32; off > 0; off >>= 1) s += __shfl_down(s, off, 64);
    if (t == 0) bo2[m] = bo[m] + s;
    if (t < 36) {
        const int k0 = t >> 2;
        const int q  = t & 3;
        const int sq = q ^ ((m >> 1) & 3);
        const int kb = k0 * 32 + sq * 8;
        const float* src = Wo + (size_t)m * CH + kb;
        unsigned short h[8];
        #pragma unroll
        for (int i = 0; i < 8; ++i) h[i] = f2b(src[i] * scale[kb + i]);
        *(uint4*)(Wop + (size_t)k0 * TILEB + m * 64 + q * 16) = *(const uint4*)h;
    }
}

// ---------------------------------------------------------------------------
// K3: MFMA GEMM2 (contiguous-GLDS) -> kerL -> fused involution.
// Block = 32 px x 288 ker-ch; LDS: [0,18432) Wo slab; [18432,20480) tmp slab;
// kerL bf16 [288][36] (20736 B) aliases all of it after the final barrier.
// ---------------------------------------------------------------------------
#define KLS 36
__global__ __launch_bounds__(256) void k_gemm2_invol(const char* __restrict__ xp,
                                                     const char* __restrict__ Wop,
                                                     const float* __restrict__ bo2,
                                                     const float* __restrict__ x,
                                                     float* __restrict__ out) {
    __shared__ short smem[10368];              // 20736 B
    char* smc = (char*)smem;
    unsigned short* kerL = (unsigned short*)smem;

    const int tid  = threadIdx.x;
    const int wave = tid >> 6;
    const int lane = tid & 63;
    const int q    = lane >> 4;
    const int r    = lane & 15;
    const int pxh  = wave & 1;
    const int chh  = wave >> 1;
    const int p0   = blockIdx.x * 32;
    const int b    = blockIdx.y;
    const int h    = p0 >> 6;
    const int w0   = p0 & 63;
    const char* tile = xp + (size_t)(b * NTILE + blockIdx.x) * TILEB;

    f32x4 acc[9];
    #pragma unroll
    for (int j = 0; j < 9; ++j) acc[j] = (f32x4)0.0f;

    const int pxl = pxh * 16 + r;
    for (int k0 = 0; k0 < 9; ++k0) {
        for (int s = wave; s < 20; s += 4) {
            const char* g = (s < 18)
                ? Wop  + (size_t)k0 * TILEB + s * 1024 + lane * 16
                : tile + (size_t)k0 * 2048 + (s - 18) * 1024 + lane * 16;
            GLDS(g, smc + s * 1024);
        }
        __syncthreads();
        const bf16x8 xf = *(const bf16x8*)(smc + 18432 + pxl * 64 +
                                           ((q ^ ((pxl >> 1) & 3)) * 16));
        #pragma unroll
        for (int j = 0; j < 9; ++j) {
            const int row = chh * 144 + j * 16 + r;
            const bf16x8 wf = *(const bf16x8*)(smc + row * 64 +
                                               ((q ^ ((row >> 1) & 3)) * 16));
            acc[j] = mfma16(wf, xf, acc[j]);
        }
        __syncthreads();
    }

    // stage ker (+bias) into LDS: kerL[c][px_loc]
    #pragma unroll
    for (int j = 0; j < 9; ++j) {
        const int cb = chh * 144 + j * 16 + q * 4;
        const float4 bz = *(const float4*)(bo2 + cb);
        kerL[(cb + 0) * KLS + pxl] = f2b(acc[j][0] + bz.x);
        kerL[(cb + 1) * KLS + pxl] = f2b(acc[j][1] + bz.y);
        kerL[(cb + 2) * KLS + pxl] = f2b(acc[j][2] + bz.z);
        kerL[(cb + 3) * KLS + pxl] = f2b(acc[j][3] + bz.w);
    }
    __syncthreads();

    // involution: thread (tm,tn) -> ch = tm+32i, px quad tn
    const int tm = tid >> 3;
    const int tn = tid & 7;
    const int wb = w0 + tn * 4;
    #pragma unroll 1
    for (int i = 0; i < 9; ++i) {
        const int ch = tm + 32 * i;
        const int cb = (ch / CPG) * CPG;
        float xv[3][6];
        #pragma unroll
        for (int dr = 0; dr < 3; ++dr) {
            const int hh = h + dr - 1;
            const bool rv = (hh >= 0) && (hh < IMH);
            const float* xr2 = x + ((size_t)(b * CH + ch) * IMH + (rv ? hh : 0)) * IMW;
            if (rv) {
                const float4 m4 = *(const float4*)(xr2 + wb);
                xv[dr][1] = m4.x; xv[dr][2] = m4.y; xv[dr][3] = m4.z; xv[dr][4] = m4.w;
                xv[dr][0] = (wb > 0)       ? xr2[wb - 1] : 0.0f;
                xv[dr][5] = (wb + 4 < IMW) ? xr2[wb + 4] : 0.0f;
            } else {
                #pragma unroll
                for (int j = 0; j < 6; ++j) xv[dr][j] = 0.0f;
            }
        }
        float o[4] = {0.0f, 0.0f, 0.0f, 0.0f};
        #pragma unroll
        for (int k = 0; k < 9; ++k) {
            const int dr = k / 3, dc = k % 3;
            const uint2 kk = *(const uint2*)(kerL + (cb + k) * KLS + tn * 4);
            const unsigned short* ks = (const unsigned short*)&kk;
            #pragma unroll
            for (int j = 0; j < 4; ++j)
                o[j] += b2f(ks[j]) * xv[dr][j + dc];
        }
        float4 ov = {o[0], o[1], o[2], o[3]};
        *(float4*)(out + ((size_t)(b * CH + ch) * IMH + h) * IMW + wb) = ov;
    }
}

// ---------------------------------------------------------------------------
extern "C" void kernel_launch(void* const* d_in, const int* in_sizes, int n_in,
                              void* d_out, int out_size, void* d_ws, size_t ws_size,
                              hipStream_t stream) {
    const float* x     = (const float*)d_in[0];
    const float* Wi    = (const float*)d_in[1];
    const float* bi    = (const float*)d_in[2];
    const float* gamma = (const float*)d_in[3];
    const float* beta  = (const float*)d_in[4];
    const float* Wo    = (const float*)d_in[5];
    const float* bo    = (const float*)d_in[6];
    float* out = (float*)d_out;

    char* ws = (char*)d_ws;
    char*  xp    = ws + XP_OFF;
    char*  Wip   = ws + WIP_OFF;
    char*  Wop   = ws + WOP_OFF;
    float* part  = (float*)(ws + PART_OFF);
    float* scale = (float*)(ws + SC_OFF);
    float* shift = (float*)(ws + SH_OFF);
    float* bo2   = (float*)(ws + BO2_OFF);

    k_transpose<<<dim3(NTILE, NB), 256, 0, stream>>>(x, xp);
    k_wi_pack<<<dim3(41), 256, 0, stream>>>(Wi, Wip);
    k_gemm1<<<dim3(NTILE, NB), 256, 0, stream>>>(Wip, bi, xp, part);
    k_scale<<<dim3(1), 576, 0, stream>>>(part, gamma, beta, scale, shift);
    k_fold<<<dim3(CH), 64, 0, stream>>>(Wo, bo, scale, shift, Wop, bo2);
    k_gemm2_invol<<<dim3(NTILE, NB), 256, 0, stream>>>(xp, Wop, bo2, x, out);
}